// Round 9
// baseline (1998.416 us; speedup 1.0000x reference)
//
#include <hip/hip_runtime.h>

using bf16   = __bf16;
using bf16x8 = __bf16 __attribute__((ext_vector_type(8)));
using f32x4  = float  __attribute__((ext_vector_type(4)));

// B=1024, T=64, F=256, H=1024, C=2.  Chunks of 8 timesteps, 8 chunks.
// ws layout (bytes):
//  XRs   @0           8,388,608   [8 sl][1024 b][512]  pre-swizzled (b&7) bf16
//  Dbfs  @8388608     4,718,592   [9 sl][1024][256]    pre-swizzled (b&7) bf16
//  GH0   @13107200   18,874,368   [9 sl][1024][1024]   parity buffer 0
//  GH1   @31981568   18,874,368   parity buffer 1
//  WcX3  @50855936    3,145,728   [nb24][kt8][nl128][64]  (n = g*1024+j, g<3)
//  WcH4  @54001664    8,388,608   [nb64][kt16][nl64][64]  (nl = g*16+jj)
//  Wgs   @62390272      524,288   [nb8][kt4][nl128][64]
//  bias4 @62914560       16,384   [4][1024] f32
//  hf0   @62930944    4,194,304   f32 state
//  hf1   @67125248    4,194,304
//  hb0   @71319552    2,097,152   bf16 state, pre-swizzled (b&7)<<3
//  hb1   @73416704    2,097,152
//  Gi0   @75513856   50,331,648   [8 sl][3 g][1024 b][1024 j]  parity 0
//  Gi1   @125845504  50,331,648   parity 1
// total 176,177,152 B (ws >= 221MB confirmed in R2)

__device__ __forceinline__ float sigm(float x) { return 1.f / (1.f + __expf(-x)); }
__device__ __forceinline__ float tanh_fast(float x) {
  float e = __expf(2.f * x);
  return 1.f - 2.f / (e + 1.f);
}

#define GLL16(gsrc, ldst)                                                              \
  __builtin_amdgcn_global_load_lds((const __attribute__((address_space(1))) void*)(gsrc), \
                                   (__attribute__((address_space(3))) void*)(ldst), 16, 0, 0)

// ---------------------------------------------------------------------------
// prep: chunk of 8 steps (+1 lookahead slice for Dbfs)
// ---------------------------------------------------------------------------
__global__ void prep_kernel(const float* __restrict__ X, const float* __restrict__ Msk,
                            const float* __restrict__ D, const float* __restrict__ Mean,
                            const float* __restrict__ L, const float* __restrict__ w_gx,
                            const float* __restrict__ b_gx,
                            bf16* __restrict__ XRs, bf16* __restrict__ Dbfs,
                            int c, int nsl) {
  int i = blockIdx.x * 256 + threadIdx.x;
  if (i >= (nsl << 18)) return;
  int f = i & 255, b = (i >> 8) & 1023, tl = i >> 18;
  int t = c * 8 + tl;
  size_t g = ((size_t)b << 14) + ((size_t)t << 8) + f;
  float d = D[g];
  int fs = f ^ ((b & 7) << 3);
  int row = tl * 1024 + b;
  Dbfs[(size_t)row * 256 + fs] = (bf16)d;
  float gx = __expf(-fmaxf(d * w_gx[f] + b_gx[f], 0.f));
  float xh = gx * L[g] + (1.f - gx) * Mean[(size_t)b * 256 + f];
  float m  = Msk[g];
  float xr = m * X[g] + (1.f - m) * xh;
  if (tl < 8) {
    size_t xo = (size_t)row * 512;
    XRs[xo + fs]       = (bf16)xr;
    XRs[xo + 256 + fs] = (bf16)m;
  }
}

// ---------------------------------------------------------------------------
// wprep: WcH4 (R4 64-col layout) + WcX3 + Wgs + bias4
// ---------------------------------------------------------------------------
__global__ void wprep_kernel(const float* __restrict__ w_ih, const float* __restrict__ w_hh,
                             const float* __restrict__ b_ih, const float* __restrict__ b_hh,
                             const float* __restrict__ w_gh,
                             bf16* __restrict__ WcH4, bf16* __restrict__ WcX3,
                             bf16* __restrict__ Wgs, float* __restrict__ bias4) {
  int i = blockIdx.x * 256 + threadIdx.x;
  if (i < 4194304) {                       // WcH4: [nb64][kt16][nl64][c8][e8], nl=g*16+jj
    int blk = i >> 12;
    int nb = blk >> 4, kt = blk & 15;
    int r = i & 4095;
    int nl = r >> 6, cc = (r >> 3) & 7, e = r & 7;
    int gg = nl >> 4, j = nb * 16 + (nl & 15);
    int k = kt * 64 + ((cc ^ (nl & 7)) << 3) + e;
    float v;
    if (gg == 3) v = w_hh[(size_t)(2048 + j) * 1024 + k];
    else {
      int rr = gg * 1024 + j;
      v = w_ih[(size_t)rr * 1536 + 256 + k];
      if (gg < 2) v += w_hh[(size_t)rr * 1024 + k];
    }
    WcH4[i] = (bf16)v;
  } else if (i < 5767168) {                // WcX3: [nb24][kt8][nl128][c8][e8], n=g*1024+j
    int q = i - 4194304;
    int blk = q >> 13;
    int nb = blk >> 3, kt = blk & 7;
    int r = q & 8191;
    int nl = r >> 6, cc = (r >> 3) & 7, e = r & 7;
    int gg = nb >> 3;                       // 0..2
    int j  = (nb & 7) * 128 + nl;
    int rr = gg * 1024 + j;
    int k = kt * 64 + ((cc ^ (nl & 7)) << 3) + e;
    float v = (k < 256) ? w_ih[(size_t)rr * 1536 + k]
                        : w_ih[(size_t)rr * 1536 + 1280 + (k - 256)];
    WcX3[q] = (bf16)v;
  } else if (i < 6029312) {                // Wgs
    int q = i - 5767168;
    int blk = q >> 13;
    int nb = blk >> 2, kt = blk & 3;
    int r = q & 8191;
    int nl = r >> 6, cc = (r >> 3) & 7, e = r & 7;
    int n = nb * 128 + nl;
    int k = kt * 64 + ((cc ^ (nl & 7)) << 3) + e;
    Wgs[q] = (bf16)w_gh[(size_t)n * 256 + k];
  } else if (i < 6033408) {                // bias4
    int q = i - 6029312;
    int gg = q >> 10, j = q & 1023;
    float v;
    if (gg == 0)      v = b_ih[j] + b_hh[j];
    else if (gg == 1) v = b_ih[1024 + j] + b_hh[1024 + j];
    else if (gg == 2) v = b_ih[2048 + j];
    else              v = b_hh[2048 + j];
    bias4[q] = v;
  }
}

// ---------------------------------------------------------------------------
// fused: [0,nstep) step blocks | [nstep, +192*gxn) gix slice | rest gammah
// 256 threads, 32KB LDS (5-block/CU capacity; 4 step blocks + 1 carry block)
// ---------------------------------------------------------------------------
__global__ __launch_bounds__(256) void fused_kernel(
    // step role
    const bf16* __restrict__ hbs, const float* __restrict__ hf,
    const bf16* __restrict__ WcH4, const float* __restrict__ bias4,
    const bf16* __restrict__ gi, const bf16* __restrict__ gh_next, int is_last,
    float* __restrict__ hf_next, bf16* __restrict__ hbs_next, int nstep,
    // gix carry (writes GiW parity buffer)
    const bf16* __restrict__ XRs, const bf16* __restrict__ WcX3,
    bf16* __restrict__ GiW, int gxb, int gxn,
    // gammah carry (writes GHW parity buffer)
    const bf16* __restrict__ Dbfs, const bf16* __restrict__ Wgs,
    const float* __restrict__ b_gh, bf16* __restrict__ GHW,
    int gmb, int gmn, int gmx) {
  __shared__ char smem[32768];
  int bid = blockIdx.x;
  int tid = threadIdx.x, lane = tid & 63, wid = tid >> 6;

  if (bid < nstep) {
    // ---------------- step role: 64x64 tile, R4 structure ----------------
    char* As = smem;            // [2][8192]
    char* Bs = smem + 16384;    // [2][8192]
    int wg = ((bid & 7) << 7) + (bid >> 3);
    int mb = wg & 15, nb = wg >> 4;

    const bf16* aA = hbs + ((size_t)(mb * 64 + wid * 8 + (lane >> 3))) * 1024 + (lane & 7) * 8;
    const bf16* aB = WcH4 + (size_t)nb * 65536 + (wid * 8 + (lane >> 3)) * 64 + (lane & 7) * 8;

    int j = nb * 16 + (lane & 15);
    float grv[4], gzv[4], gnv[4], ghv[4], hfv[4];
#pragma unroll
    for (int reg = 0; reg < 4; ++reg) {
      int brow = mb * 64 + wid * 16 + ((lane >> 4) << 2) + reg;
      size_t hb_ = (size_t)brow * 1024 + j;
      grv[reg] = (float)gi[hb_];
      gzv[reg] = (float)gi[1048576 + hb_];
      gnv[reg] = (float)gi[2097152 + hb_];
      ghv[reg] = (float)gh_next[hb_];
      hfv[reg] = hf[hb_];
    }

    f32x4 acc[4];
#pragma unroll
    for (int b = 0; b < 4; ++b)
#pragma unroll
      for (int q = 0; q < 4; ++q) acc[b][q] = 0.f;

#define STP_STAGE(buf, kt)                                                   \
  do {                                                                       \
    GLL16(aA + (kt) * 64,             As + (buf) * 8192 + wid * 1024);       \
    GLL16(aA + 32 * 1024 + (kt) * 64, As + (buf) * 8192 + (wid + 4) * 1024); \
    GLL16(aB + (kt) * 4096,           Bs + (buf) * 8192 + wid * 1024);       \
    GLL16(aB + (kt) * 4096 + 2048,    Bs + (buf) * 8192 + (wid + 4) * 1024); \
  } while (0)

    STP_STAGE(0, 0);
    __syncthreads();
    for (int kt = 0; kt < 16; ++kt) {
      const int cur = kt & 1;
      if (kt < 15) STP_STAGE(cur ^ 1, kt + 1);
#pragma unroll
      for (int kk = 0; kk < 2; ++kk) {
        int kb = kk * 64 + ((lane >> 4) << 4);
        int row = wid * 16 + (lane & 15);
        bf16x8 af = *(const bf16x8*)(As + cur * 8192 + (((row * 128 + kb)) ^ ((row & 7) << 4)));
        bf16x8 bfr[4];
#pragma unroll
        for (int g = 0; g < 4; ++g) {
          int nl = g * 16 + (lane & 15);
          bfr[g] = *(const bf16x8*)(Bs + cur * 8192 + (((nl * 128 + kb)) ^ ((nl & 7) << 4)));
        }
#pragma unroll
        for (int g = 0; g < 4; ++g)
          acc[g] = __builtin_amdgcn_mfma_f32_16x16x32_bf16(af, bfr[g], acc[g], 0, 0, 0);
      }
      __syncthreads();
    }

    float br = bias4[j], bz = bias4[1024 + j], bn = bias4[2048 + j], bh = bias4[3072 + j];
#pragma unroll
    for (int reg = 0; reg < 4; ++reg) {
      int brow = mb * 64 + wid * 16 + ((lane >> 4) << 2) + reg;
      float pr  = acc[0][reg] + grv[reg] + br;
      float pz  = acc[1][reg] + gzv[reg] + bz;
      float pin = acc[2][reg] + gnv[reg] + bn;
      float phn = acc[3][reg] + bh;
      float r = sigm(pr), z = sigm(pz);
      float nn = tanh_fast(pin + r * phn);
      float hnew = (1.f - z) * nn + z * hfv[reg];
      float gam = is_last ? 1.f : ghv[reg];
      float hd = hnew * gam;
      hf_next[(size_t)brow * 1024 + j] = hd;
      hbs_next[(size_t)brow * 1024 + (j ^ ((brow & 7) << 3))] = (bf16)hd;
    }
    return;
  }

  int r0 = bid - nstep;
  if (r0 < 192 * gxn) {
    // ---------------- gix role: 128x128, K=512, single-buffered ----------------
    int gxsl = gxb + r0 / 192;
    int sub  = r0 % 192;
    int wr = wid >> 1, wc = wid & 1;
    int nb = sub % 24, mb = sub / 24;
    char* As = smem;           // 16KB
    char* Bs = smem + 16384;   // 16KB

    const bf16* aA = XRs + ((size_t)(gxsl * 1024 + mb * 128 + wid * 8 + (lane >> 3))) * 512 + (lane & 7) * 8;
    const bf16* aB = WcX3 + (size_t)nb * 65536 + wid * 512 + lane * 8;

    f32x4 acc[4][4];
#pragma unroll
    for (int a = 0; a < 4; ++a)
#pragma unroll
      for (int b = 0; b < 4; ++b)
#pragma unroll
        for (int q = 0; q < 4; ++q) acc[a][b][q] = 0.f;

    for (int kt = 0; kt < 8; ++kt) {
#pragma unroll
      for (int q = 0; q < 4; ++q)
        GLL16(aA + q * (32 * 512) + kt * 64, As + (q * 4 + wid) * 1024);
#pragma unroll
      for (int q = 0; q < 4; ++q)
        GLL16(aB + kt * 8192 + q * 2048, Bs + (q * 4 + wid) * 1024);
      __syncthreads();
#pragma unroll
      for (int kk = 0; kk < 2; ++kk) {
        int kb = kk * 64 + ((lane >> 4) << 4);
        bf16x8 af[4], bfr[4];
#pragma unroll
        for (int mf = 0; mf < 4; ++mf) {
          int row = wr * 64 + mf * 16 + (lane & 15);
          af[mf] = *(const bf16x8*)(As + (((row * 128 + kb)) ^ ((row & 7) << 4)));
        }
#pragma unroll
        for (int nf = 0; nf < 4; ++nf) {
          int nl = wc * 64 + nf * 16 + (lane & 15);
          bfr[nf] = *(const bf16x8*)(Bs + (((nl * 128 + kb)) ^ ((nl & 7) << 4)));
        }
#pragma unroll
        for (int mf = 0; mf < 4; ++mf)
#pragma unroll
          for (int nf = 0; nf < 4; ++nf)
            acc[mf][nf] = __builtin_amdgcn_mfma_f32_16x16x32_bf16(af[mf], bfr[nf], acc[mf][nf], 0, 0, 0);
      }
      __syncthreads();
    }
    char* ep = smem;
#pragma unroll
    for (int nf = 0; nf < 4; ++nf) {
      int col = wc * 64 + nf * 16 + (lane & 15);
#pragma unroll
      for (int mf = 0; mf < 4; ++mf)
#pragma unroll
        for (int reg = 0; reg < 4; ++reg) {
          int row = wr * 64 + mf * 16 + ((lane >> 4) << 2) + reg;
          int cph = ((col >> 3) ^ (((row >> 2) & 3) << 2));
          *(bf16*)(ep + row * 256 + (cph << 4) + (col & 7) * 2) = (bf16)acc[mf][nf][reg];
        }
    }
    __syncthreads();
    bf16* plane = GiW + (size_t)gxsl * 3145728 + (size_t)(nb >> 3) * 1048576 + (nb & 7) * 128;
#pragma unroll
    for (int p = 0; p < 8; ++p) {
      int idx = p * 256 + tid;
      int row = idx >> 4, cc = idx & 15;
      int cph = cc ^ (((row >> 2) & 3) << 2);
      bf16x8 v = *(const bf16x8*)(ep + row * 256 + (cph << 4));
      *(bf16x8*)(plane + (size_t)(mb * 128 + row) * 1024 + cc * 8) = v;
    }
    return;
  }

  // ---------------- gammah role: 128x128, K=256, single-buffered ----------------
  int r1 = r0 - 192 * gxn;
  int gmsl, sub;
  if (r1 < 64 * gmn) { gmsl = gmb + r1 / 64; sub = r1 % 64; }
  else               { gmsl = gmx;           sub = r1 - 64 * gmn; }
  {
    int wr = wid >> 1, wc = wid & 1;
    int mb = sub >> 3, nb = sub & 7;
    char* As = smem;
    char* Bs = smem + 16384;

    const bf16* aA = Dbfs + ((size_t)(gmsl * 1024 + mb * 128 + wid * 8 + (lane >> 3))) * 256 + (lane & 7) * 8;
    const bf16* aB = Wgs + (size_t)nb * 32768 + wid * 512 + lane * 8;

    f32x4 acc[4][4];
#pragma unroll
    for (int a = 0; a < 4; ++a)
#pragma unroll
      for (int b = 0; b < 4; ++b)
#pragma unroll
        for (int q = 0; q < 4; ++q) acc[a][b][q] = 0.f;

    for (int kt = 0; kt < 4; ++kt) {
#pragma unroll
      for (int q = 0; q < 4; ++q)
        GLL16(aA + q * (32 * 256) + kt * 64, As + (q * 4 + wid) * 1024);
#pragma unroll
      for (int q = 0; q < 4; ++q)
        GLL16(aB + kt * 8192 + q * 2048, Bs + (q * 4 + wid) * 1024);
      __syncthreads();
#pragma unroll
      for (int kk = 0; kk < 2; ++kk) {
        int kb = kk * 64 + ((lane >> 4) << 4);
        bf16x8 af[4], bfr[4];
#pragma unroll
        for (int mf = 0; mf < 4; ++mf) {
          int row = wr * 64 + mf * 16 + (lane & 15);
          af[mf] = *(const bf16x8*)(As + (((row * 128 + kb)) ^ ((row & 7) << 4)));
        }
#pragma unroll
        for (int nf = 0; nf < 4; ++nf) {
          int nl = wc * 64 + nf * 16 + (lane & 15);
          bfr[nf] = *(const bf16x8*)(Bs + (((nl * 128 + kb)) ^ ((nl & 7) << 4)));
        }
#pragma unroll
        for (int mf = 0; mf < 4; ++mf)
#pragma unroll
          for (int nf = 0; nf < 4; ++nf)
            acc[mf][nf] = __builtin_amdgcn_mfma_f32_16x16x32_bf16(af[mf], bfr[nf], acc[mf][nf], 0, 0, 0);
      }
      __syncthreads();
    }
    char* ep = smem;
#pragma unroll
    for (int nf = 0; nf < 4; ++nf) {
      int col = wc * 64 + nf * 16 + (lane & 15);
      float bg = b_gh[nb * 128 + col];
#pragma unroll
      for (int mf = 0; mf < 4; ++mf)
#pragma unroll
        for (int reg = 0; reg < 4; ++reg) {
          int row = wr * 64 + mf * 16 + ((lane >> 4) << 2) + reg;
          int cph = ((col >> 3) ^ (((row >> 2) & 3) << 2));
          *(bf16*)(ep + row * 256 + (cph << 4) + (col & 7) * 2) =
              (bf16)__expf(-fmaxf(acc[mf][nf][reg] + bg, 0.f));
        }
    }
    __syncthreads();
    bf16* gout = GHW + (size_t)gmsl * 1048576;
#pragma unroll
    for (int p = 0; p < 8; ++p) {
      int idx = p * 256 + tid;
      int row = idx >> 4, cc = idx & 15;
      int cph = cc ^ (((row >> 2) & 3) << 2);
      bf16x8 v = *(const bf16x8*)(ep + row * 256 + (cph << 4));
      *(bf16x8*)(gout + (size_t)(mb * 128 + row) * 1024 + nb * 128 + cc * 8) = v;
    }
  }
}

// ---------------------------------------------------------------------------
// classifier + softmax
// ---------------------------------------------------------------------------
__global__ void cls_kernel(const float* __restrict__ h, const float* __restrict__ w_cls,
                           const float* __restrict__ b_cls, float* __restrict__ out) {
  int wid = threadIdx.x >> 6, lane = threadIdx.x & 63;
  int b = blockIdx.x * 4 + wid;
  const float* hb = h + (size_t)b * 1024;
  float a0 = 0.f, a1 = 0.f;
#pragma unroll
  for (int e = 0; e < 16; ++e) {
    int i = e * 64 + lane;
    float hv = hb[i];
    a0 += hv * w_cls[i];
    a1 += hv * w_cls[1024 + i];
  }
  for (int off = 32; off; off >>= 1) {
    a0 += __shfl_down(a0, off);
    a1 += __shfl_down(a1, off);
  }
  if (lane == 0) {
    float l0 = a0 + b_cls[0], l1 = a1 + b_cls[1];
    float mx = fmaxf(l0, l1);
    float e0 = __expf(l0 - mx), e1 = __expf(l1 - mx);
    float s = e0 + e1;
    out[b * 2]     = e0 / s;
    out[b * 2 + 1] = e1 / s;
  }
}

// ---------------------------------------------------------------------------
extern "C" void kernel_launch(void* const* d_in, const int* in_sizes, int n_in,
                              void* d_out, int out_size, void* d_ws, size_t ws_size,
                              hipStream_t stream) {
  const float* X     = (const float*)d_in[0];
  const float* Msk   = (const float*)d_in[1];
  const float* D     = (const float*)d_in[2];
  const float* Mean  = (const float*)d_in[3];
  const float* L     = (const float*)d_in[4];
  const float* w_gh  = (const float*)d_in[5];
  const float* b_gh  = (const float*)d_in[6];
  const float* w_gx  = (const float*)d_in[7];
  const float* b_gx  = (const float*)d_in[8];
  const float* w_ih  = (const float*)d_in[9];
  const float* w_hh  = (const float*)d_in[10];
  const float* b_ih  = (const float*)d_in[11];
  const float* b_hh  = (const float*)d_in[12];
  const float* w_cls = (const float*)d_in[13];
  const float* b_cls = (const float*)d_in[14];

  char* w = (char*)d_ws;
  bf16*  XRs   = (bf16*)(w);
  bf16*  Dbfs  = (bf16*)(w + 8388608);
  bf16*  GHb[2] = {(bf16*)(w + 13107200), (bf16*)(w + 31981568)};
  bf16*  WcX3  = (bf16*)(w + 50855936);
  bf16*  WcH4  = (bf16*)(w + 54001664);
  bf16*  Wgs   = (bf16*)(w + 62390272);
  float* bias4 = (float*)(w + 62914560);
  float* hfp[2] = {(float*)(w + 62930944), (float*)(w + 67125248)};
  bf16*  hbp[2] = {(bf16*)(w + 71319552), (bf16*)(w + 73416704)};
  bf16*  Gib[2] = {(bf16*)(w + 75513856), (bf16*)(w + 125845504)};

  hipMemsetAsync(hfp[0], 0, 4194304, stream);
  hipMemsetAsync(hbp[0], 0, 2097152, stream);
  wprep_kernel<<<23568, 256, 0, stream>>>(w_ih, w_hh, b_ih, b_hh, w_gh, WcH4, WcX3, Wgs, bias4);

  // chunk 0 pre-work: prep(0) + all gix/gammah slices of chunk 0
  prep_kernel<<<9 * 1024, 256, 0, stream>>>(X, Msk, D, Mean, L, w_gx, b_gx, XRs, Dbfs, 0, 9);
  fused_kernel<<<192 * 8 + 64 * 9, 256, 0, stream>>>(
      hbp[0], hfp[0], WcH4, bias4, Gib[0], GHb[0], 0, hfp[1], hbp[1], /*nstep=*/0,
      XRs, WcX3, Gib[0], /*gxb=*/0, /*gxn=*/8,
      Dbfs, Wgs, b_gh, GHb[0], /*gmb=*/0, /*gmn=*/9, /*gmx=*/-1);

  for (int c = 0; c < 8; ++c) {
    int pr = c & 1, pw = (c + 1) & 1;
    if (c < 7)   // prep next chunk before this chunk's launches (they carry c+1)
      prep_kernel<<<((c + 1 == 7) ? 8 : 9) * 1024, 256, 0, stream>>>(
          X, Msk, D, Mean, L, w_gx, b_gx, XRs, Dbfs, c + 1, (c + 1 == 7) ? 8 : 9);
    for (int i = 0; i < 8; ++i) {
      int t = c * 8 + i;
      int cur = t & 1, nxt = cur ^ 1;
      int gxn = (c < 7) ? 1 : 0;
      int gmn = (c < 7) ? 1 : 0;
      int gmx = (c < 7 && i == 0) ? 8 : -1;
      int grid = 1024 + 192 * gxn + 64 * gmn + ((gmx >= 0) ? 64 : 0);
      fused_kernel<<<grid, 256, 0, stream>>>(
          hbp[cur], hfp[cur], WcH4, bias4,
          Gib[pr] + (size_t)i * 3145728, GHb[pr] + (size_t)(i + 1) * 1048576,
          (t == 63) ? 1 : 0, hfp[nxt], hbp[nxt], /*nstep=*/1024,
          XRs, WcX3, Gib[pw], /*gxb=*/i, gxn,
          Dbfs, Wgs, b_gh, GHb[pw], /*gmb=*/i, gmn, gmx);
    }
  }
  cls_kernel<<<256, 256, 0, stream>>>(hfp[0], w_cls, b_cls, (float*)d_out);
}

// Round 10
// 1386.669 us; speedup vs baseline: 1.4412x; 1.4412x over previous
//
#include <hip/hip_runtime.h>

using bf16   = __bf16;
using bf16x8 = __bf16 __attribute__((ext_vector_type(8)));
using f32x4  = float  __attribute__((ext_vector_type(4)));

// B=1024, T=64, F=256, H=1024, C=2
// ws layout: identical to R7.

__device__ __forceinline__ float sigm(float x) { return 1.f / (1.f + __expf(-x)); }
__device__ __forceinline__ float tanh_fast(float x) {
  float e = __expf(2.f * x);
  return 1.f - 2.f / (e + 1.f);
}

#define GLL16(gsrc, ldst)                                                              \
  __builtin_amdgcn_global_load_lds((const __attribute__((address_space(1))) void*)(gsrc), \
                                   (__attribute__((address_space(3))) void*)(ldst), 16, 0, 0)

// ---------------------------------------------------------------------------
// prep: pre-swizzled XRs ([xr|m], f XOR (b&7)<<3) and Dbfs
// ---------------------------------------------------------------------------
__global__ void prep_kernel(const float* __restrict__ X, const float* __restrict__ Msk,
                            const float* __restrict__ D, const float* __restrict__ Mean,
                            const float* __restrict__ L, const float* __restrict__ w_gx,
                            const float* __restrict__ b_gx,
                            bf16* __restrict__ XRs, bf16* __restrict__ Dbfs,
                            int c, int nsl) {
  int i = blockIdx.x * 256 + threadIdx.x;
  if (i >= (nsl << 18)) return;
  int f = i & 255, b = (i >> 8) & 1023, tl = i >> 18;
  int t = c * 16 + tl;
  size_t g = ((size_t)b << 14) + ((size_t)t << 8) + f;
  float d = D[g];
  int fs = f ^ ((b & 7) << 3);
  int row = tl * 1024 + b;
  Dbfs[(size_t)row * 256 + fs] = (bf16)d;
  float gx = __expf(-fmaxf(d * w_gx[f] + b_gx[f], 0.f));
  float xh = gx * L[g] + (1.f - gx) * Mean[(size_t)b * 256 + f];
  float m  = Msk[g];
  float xr = m * X[g] + (1.f - m) * xh;
  if (tl < 16) {
    size_t xo = (size_t)row * 512;
    XRs[xo + fs]       = (bf16)xr;
    XRs[xo + 256 + fs] = (bf16)m;
  }
}

// ---------------------------------------------------------------------------
// wprep
// ---------------------------------------------------------------------------
__global__ void wprep_kernel(const float* __restrict__ w_ih, const float* __restrict__ w_hh,
                             const float* __restrict__ b_ih, const float* __restrict__ b_hh,
                             const float* __restrict__ w_gh,
                             bf16* __restrict__ WcH3, bf16* __restrict__ WcX3,
                             bf16* __restrict__ Wgs, float* __restrict__ bias4) {
  int i = blockIdx.x * 256 + threadIdx.x;
  if (i < 4194304) {                       // WcH3: [nb32][kt16][nl128][c8][e8], nl=g*32+jj
    int blk = i >> 13;
    int nb = blk >> 4, kt = blk & 15;
    int r = i & 8191;
    int nl = r >> 6, cc = (r >> 3) & 7, e = r & 7;
    int gg = nl >> 5, j = nb * 32 + (nl & 31);
    int k = kt * 64 + ((cc ^ (nl & 7)) << 3) + e;
    float v;
    if (gg == 3) v = w_hh[(size_t)(2048 + j) * 1024 + k];
    else {
      int rr = gg * 1024 + j;
      v = w_ih[(size_t)rr * 1536 + 256 + k];
      if (gg < 2) v += w_hh[(size_t)rr * 1024 + k];
    }
    WcH3[i] = (bf16)v;
  } else if (i < 5767168) {                // WcX3: [nb24][kt8][nl128][c8][e8], n=g*1024+j
    int q = i - 4194304;
    int blk = q >> 13;
    int nb = blk >> 3, kt = blk & 7;
    int r = q & 8191;
    int nl = r >> 6, cc = (r >> 3) & 7, e = r & 7;
    int gg = nb >> 3;                       // 0..2
    int j  = (nb & 7) * 128 + nl;
    int rr = gg * 1024 + j;
    int k = kt * 64 + ((cc ^ (nl & 7)) << 3) + e;
    float v = (k < 256) ? w_ih[(size_t)rr * 1536 + k]
                        : w_ih[(size_t)rr * 1536 + 1280 + (k - 256)];
    WcX3[q] = (bf16)v;
  } else if (i < 6029312) {                // Wgs
    int q = i - 5767168;
    int blk = q >> 13;
    int nb = blk >> 2, kt = blk & 3;
    int r = q & 8191;
    int nl = r >> 6, cc = (r >> 3) & 7, e = r & 7;
    int n = nb * 128 + nl;
    int k = kt * 64 + ((cc ^ (nl & 7)) << 3) + e;
    Wgs[q] = (bf16)w_gh[(size_t)n * 256 + k];
  } else if (i < 6033408) {                // bias4
    int q = i - 6029312;
    int gg = q >> 10, j = q & 1023;
    float v;
    if (gg == 0)      v = b_ih[j] + b_hh[j];
    else if (gg == 1) v = b_ih[1024 + j] + b_hh[1024 + j];
    else if (gg == 2) v = b_ih[2048 + j];
    else              v = b_hh[2048 + j];
    bias4[q] = v;
  }
}

// ---------------------------------------------------------------------------
// gammah: GH = exp(-relu(Dbfs . Wg^T + b_gh)); R4 2-phase, nb-fastest
// ---------------------------------------------------------------------------
__global__ __launch_bounds__(256) void gammah_kernel(const bf16* __restrict__ Dbfs,
                                                     const bf16* __restrict__ Wgs,
                                                     const float* __restrict__ b_gh,
                                                     bf16* __restrict__ GH) {
  __shared__ char smem[65536];
  char* As = smem;            // [2][16384]
  char* Bs = smem + 32768;    // [2][16384]
  int tid = threadIdx.x, lane = tid & 63, wid = tid >> 6;
  int wr = wid >> 1, wc = wid & 1;
  int cpx = gridDim.x >> 3;
  int wg = (blockIdx.x & 7) * cpx + (blockIdx.x >> 3);
  int nb = wg & 7, mb = wg >> 3;

  const bf16* aA = Dbfs + ((size_t)(mb * 128 + wid * 8 + (lane >> 3))) * 256 + (lane & 7) * 8;
  const bf16* aB = Wgs + (size_t)nb * 4 * 8192 + wid * 512 + lane * 8;

  f32x4 acc[4][4];
#pragma unroll
  for (int a = 0; a < 4; ++a)
#pragma unroll
    for (int b = 0; b < 4; ++b)
#pragma unroll
      for (int q = 0; q < 4; ++q) acc[a][b][q] = 0.f;

#define GM_STAGE(buf, kt)                                                         \
  do {                                                                            \
    _Pragma("unroll")                                                             \
    for (int q = 0; q < 4; ++q)                                                   \
      GLL16(aA + q * (32 * 256) + (kt) * 64, As + (buf) * 16384 + (q * 4 + wid) * 1024); \
    _Pragma("unroll")                                                             \
    for (int q = 0; q < 4; ++q)                                                   \
      GLL16(aB + (size_t)(kt) * 8192 + q * 2048, Bs + (buf) * 16384 + (q * 4 + wid) * 1024); \
  } while (0)

  GM_STAGE(0, 0);
  __syncthreads();
  for (int kt = 0; kt < 4; ++kt) {
    const int cur = kt & 1;
    if (kt < 3) GM_STAGE(cur ^ 1, kt + 1);
#pragma unroll
    for (int kk = 0; kk < 2; ++kk) {
      int kb = kk * 64 + ((lane >> 4) << 4);
      bf16x8 af[4], bfr[4];
#pragma unroll
      for (int mf = 0; mf < 4; ++mf) {
        int row = wr * 64 + mf * 16 + (lane & 15);
        af[mf] = *(const bf16x8*)(As + cur * 16384 + (((row * 128 + kb)) ^ ((row & 7) << 4)));
      }
#pragma unroll
      for (int nf = 0; nf < 4; ++nf) {
        int nl = wc * 64 + nf * 16 + (lane & 15);
        bfr[nf] = *(const bf16x8*)(Bs + cur * 16384 + (((nl * 128 + kb)) ^ ((nl & 7) << 4)));
      }
#pragma unroll
      for (int mf = 0; mf < 4; ++mf)
#pragma unroll
        for (int nf = 0; nf < 4; ++nf)
          acc[mf][nf] = __builtin_amdgcn_mfma_f32_16x16x32_bf16(af[mf], bfr[nf], acc[mf][nf], 0, 0, 0);
    }
    __syncthreads();
  }
  char* ep = smem;   // 128 rows x 256B
#pragma unroll
  for (int nf = 0; nf < 4; ++nf) {
    int col = wc * 64 + nf * 16 + (lane & 15);
    float bg = b_gh[nb * 128 + col];
#pragma unroll
    for (int mf = 0; mf < 4; ++mf)
#pragma unroll
      for (int reg = 0; reg < 4; ++reg) {
        int row = wr * 64 + mf * 16 + ((lane >> 4) << 2) + reg;
        int cph = ((col >> 3) ^ (((row >> 2) & 3) << 2));
        *(bf16*)(ep + row * 256 + (cph << 4) + (col & 7) * 2) =
            (bf16)__expf(-fmaxf(acc[mf][nf][reg] + bg, 0.f));
      }
  }
  __syncthreads();
#pragma unroll
  for (int p = 0; p < 8; ++p) {
    int idx = p * 256 + tid;
    int row = idx >> 4, c = idx & 15;
    int cph = c ^ (((row >> 2) & 3) << 2);
    bf16x8 v = *(const bf16x8*)(ep + row * 256 + (cph << 4));
    *(bf16x8*)(GH + (size_t)(mb * 128 + row) * 1024 + nb * 128 + c * 8) = v;
  }
}

// ---------------------------------------------------------------------------
// gix: Gi[slice][g][b][j] = XRs . WcX^T (3 gate planes); R4 2-phase, nb-fastest
// ---------------------------------------------------------------------------
__global__ __launch_bounds__(256) void gix_kernel(const bf16* __restrict__ XRs,
                                                  const bf16* __restrict__ WcX3,
                                                  bf16* __restrict__ Gi) {
  __shared__ char smem[65536];
  char* As = smem;
  char* Bs = smem + 32768;
  int tid = threadIdx.x, lane = tid & 63, wid = tid >> 6;
  int wr = wid >> 1, wc = wid & 1;
  int cpx = gridDim.x >> 3;
  int wg = (blockIdx.x & 7) * cpx + (blockIdx.x >> 3);
  int nb = wg % 24, mb = wg / 24;

  const bf16* aA = XRs + ((size_t)(mb * 128 + wid * 8 + (lane >> 3))) * 512 + (lane & 7) * 8;
  const bf16* aB = WcX3 + (size_t)nb * 8 * 8192 + wid * 512 + lane * 8;

  f32x4 acc[4][4];
#pragma unroll
  for (int a = 0; a < 4; ++a)
#pragma unroll
    for (int b = 0; b < 4; ++b)
#pragma unroll
      for (int q = 0; q < 4; ++q) acc[a][b][q] = 0.f;

#define GX_STAGE(buf, kt)                                                         \
  do {                                                                            \
    _Pragma("unroll")                                                             \
    for (int q = 0; q < 4; ++q)                                                   \
      GLL16(aA + q * (32 * 512) + (kt) * 64, As + (buf) * 16384 + (q * 4 + wid) * 1024); \
    _Pragma("unroll")                                                             \
    for (int q = 0; q < 4; ++q)                                                   \
      GLL16(aB + (size_t)(kt) * 8192 + q * 2048, Bs + (buf) * 16384 + (q * 4 + wid) * 1024); \
  } while (0)

  GX_STAGE(0, 0);
  __syncthreads();
  for (int kt = 0; kt < 8; ++kt) {
    const int cur = kt & 1;
    if (kt < 7) GX_STAGE(cur ^ 1, kt + 1);
#pragma unroll
    for (int kk = 0; kk < 2; ++kk) {
      int kb = kk * 64 + ((lane >> 4) << 4);
      bf16x8 af[4], bfr[4];
#pragma unroll
      for (int mf = 0; mf < 4; ++mf) {
        int row = wr * 64 + mf * 16 + (lane & 15);
        af[mf] = *(const bf16x8*)(As + cur * 16384 + (((row * 128 + kb)) ^ ((row & 7) << 4)));
      }
#pragma unroll
      for (int nf = 0; nf < 4; ++nf) {
        int nl = wc * 64 + nf * 16 + (lane & 15);
        bfr[nf] = *(const bf16x8*)(Bs + cur * 16384 + (((nl * 128 + kb)) ^ ((nl & 7) << 4)));
      }
#pragma unroll
      for (int mf = 0; mf < 4; ++mf)
#pragma unroll
        for (int nf = 0; nf < 4; ++nf)
          acc[mf][nf] = __builtin_amdgcn_mfma_f32_16x16x32_bf16(af[mf], bfr[nf], acc[mf][nf], 0, 0, 0);
    }
    __syncthreads();
  }
  char* ep = smem;
#pragma unroll
  for (int nf = 0; nf < 4; ++nf) {
    int col = wc * 64 + nf * 16 + (lane & 15);
#pragma unroll
    for (int mf = 0; mf < 4; ++mf)
#pragma unroll
      for (int reg = 0; reg < 4; ++reg) {
        int row = wr * 64 + mf * 16 + ((lane >> 4) << 2) + reg;
        int cph = ((col >> 3) ^ (((row >> 2) & 3) << 2));
        *(bf16*)(ep + row * 256 + (cph << 4) + (col & 7) * 2) = (bf16)acc[mf][nf][reg];
      }
  }
  __syncthreads();
  {
    int sl = mb >> 3, mbl = mb & 7;
    bf16* plane = Gi + (size_t)sl * 3145728 + (size_t)(nb >> 3) * 1048576 + (nb & 7) * 128;
#pragma unroll
    for (int p = 0; p < 8; ++p) {
      int idx = p * 256 + tid;
      int row = idx >> 4, c = idx & 15;
      int cph = c ^ (((row >> 2) & 3) << 2);
      bf16x8 v = *(const bf16x8*)(ep + row * 256 + (cph << 4));
      *(bf16x8*)(plane + (size_t)(mbl * 128 + row) * 1024 + c * 8) = v;
    }
  }
}

// ---------------------------------------------------------------------------
// step: 64x128 tile, 512 threads, grid 512 (2 blocks/CU), 2-buffer
// counted-vmcnt pipeline (1-deep): stage(k+1) stays in flight across the
// barrier; wait only for stage(k) via in-order vmcnt retirement.
// ---------------------------------------------------------------------------
__global__ __launch_bounds__(512) void step_kernel(
    const bf16* __restrict__ hbs, const float* __restrict__ hf,
    const bf16* __restrict__ WcH3, const float* __restrict__ bias4,
    const bf16* __restrict__ gi, const bf16* __restrict__ gh_next, int is_last,
    float* __restrict__ hf_next, bf16* __restrict__ hbs_next) {
  __shared__ char smem[49152];   // A [2][8192] @0, B [2][16384] @16384
  int tid = threadIdx.x, lane = tid & 63, wid = tid >> 6;
  int wr = wid >> 1, wc = wid & 1;
  int wg = ((blockIdx.x & 7) << 6) + (blockIdx.x >> 3);
  int mb = wg & 15, nb = wg >> 4;

  const bf16* aA = hbs + ((size_t)(mb * 64 + (tid >> 3))) * 1024 + (tid & 7) * 8;
  const bf16* aB = WcH3 + (size_t)nb * 131072 + tid * 8;

  // ---- epilogue prefetch (oldest in vmcnt order; waits below are safe) ----
  int j = nb * 32 + wc * 16 + (lane & 15);
  bf16  grv[4], gzv[4], gnv[4], ghv[4];
  float hfv[4];
#pragma unroll
  for (int reg = 0; reg < 4; ++reg) {
    int brow = mb * 64 + wr * 16 + ((lane >> 4) << 2) + reg;
    size_t hb_ = (size_t)brow * 1024 + j;
    grv[reg] = gi[hb_];
    gzv[reg] = gi[1048576 + hb_];
    gnv[reg] = gi[2097152 + hb_];
    ghv[reg] = gh_next[hb_];
    hfv[reg] = hf[hb_];
  }

  f32x4 acc[4];
#pragma unroll
  for (int b = 0; b < 4; ++b)
#pragma unroll
    for (int q = 0; q < 4; ++q) acc[b][q] = 0.f;

#define ST_STAGE(buf, kt)                                                         \
  do {                                                                            \
    GLL16(aA + (kt) * 64,                 smem + (buf) * 8192 + wid * 1024);      \
    GLL16(aB + (kt) * 8192,               smem + 16384 + (buf) * 16384 + wid * 1024); \
    GLL16(aB + (kt) * 8192 + 4096,        smem + 16384 + (buf) * 16384 + 8192 + wid * 1024); \
  } while (0)

  ST_STAGE(0, 0);
  for (int kt = 0; kt < 16; ++kt) {
    const int cur = kt & 1;
    if (kt < 15) {
      ST_STAGE(cur ^ 1, kt + 1);
      // in-order retire: outstanding<=3 guarantees stage(kt) landed,
      // while stage(kt+1)'s 3 loads may remain in flight across the barrier.
      asm volatile("s_waitcnt vmcnt(3)" ::: "memory");
    } else {
      asm volatile("s_waitcnt vmcnt(0)" ::: "memory");
    }
    __builtin_amdgcn_sched_barrier(0);
    __builtin_amdgcn_s_barrier();
    __builtin_amdgcn_sched_barrier(0);
    const char* Ab = smem + cur * 8192;
    const char* Bb = smem + 16384 + cur * 16384;
#pragma unroll
    for (int kk = 0; kk < 2; ++kk) {
      int kb = kk * 64 + ((lane >> 4) << 4);
      int row = wr * 16 + (lane & 15);
      bf16x8 af = *(const bf16x8*)(Ab + (((row * 128 + kb)) ^ ((row & 7) << 4)));
      bf16x8 bfr[4];
#pragma unroll
      for (int g = 0; g < 4; ++g) {
        int nl = g * 32 + wc * 16 + (lane & 15);
        bfr[g] = *(const bf16x8*)(Bb + (((nl * 128 + kb)) ^ ((nl & 7) << 4)));
      }
#pragma unroll
      for (int g = 0; g < 4; ++g)
        acc[g] = __builtin_amdgcn_mfma_f32_16x16x32_bf16(af, bfr[g], acc[g], 0, 0, 0);
    }
    // WAR guard: all LDS reads of buf `cur` must retire before any wave's
    // next-iter ST_STAGE overwrites it (next iter stages into buf cur).
    asm volatile("s_waitcnt lgkmcnt(0)" ::: "memory");
    __builtin_amdgcn_sched_barrier(0);
    __builtin_amdgcn_s_barrier();
  }

  // fused GRU epilogue (direct stores)
  float br = bias4[j], bz = bias4[1024 + j], bn = bias4[2048 + j], bh = bias4[3072 + j];
#pragma unroll
  for (int reg = 0; reg < 4; ++reg) {
    int brow = mb * 64 + wr * 16 + ((lane >> 4) << 2) + reg;
    float pr  = acc[0][reg] + (float)grv[reg] + br;
    float pz  = acc[1][reg] + (float)gzv[reg] + bz;
    float pin = acc[2][reg] + (float)gnv[reg] + bn;
    float phn = acc[3][reg] + bh;
    float r = sigm(pr), z = sigm(pz);
    float nn = tanh_fast(pin + r * phn);
    float hnew = (1.f - z) * nn + z * hfv[reg];
    float gam = is_last ? 1.f : (float)ghv[reg];
    float hd = hnew * gam;
    hf_next[(size_t)brow * 1024 + j] = hd;
    hbs_next[(size_t)brow * 1024 + (j ^ ((brow & 7) << 3))] = (bf16)hd;
  }
}

// ---------------------------------------------------------------------------
// classifier + softmax
// ---------------------------------------------------------------------------
__global__ void cls_kernel(const float* __restrict__ h, const float* __restrict__ w_cls,
                           const float* __restrict__ b_cls, float* __restrict__ out) {
  int wid = threadIdx.x >> 6, lane = threadIdx.x & 63;
  int b = blockIdx.x * 4 + wid;
  const float* hb = h + (size_t)b * 1024;
  float a0 = 0.f, a1 = 0.f;
#pragma unroll
  for (int e = 0; e < 16; ++e) {
    int i = e * 64 + lane;
    float hv = hb[i];
    a0 += hv * w_cls[i];
    a1 += hv * w_cls[1024 + i];
  }
  for (int off = 32; off; off >>= 1) {
    a0 += __shfl_down(a0, off);
    a1 += __shfl_down(a1, off);
  }
  if (lane == 0) {
    float l0 = a0 + b_cls[0], l1 = a1 + b_cls[1];
    float mx = fmaxf(l0, l1);
    float e0 = __expf(l0 - mx), e1 = __expf(l1 - mx);
    float s = e0 + e1;
    out[b * 2]     = e0 / s;
    out[b * 2 + 1] = e1 / s;
  }
}

// ---------------------------------------------------------------------------
extern "C" void kernel_launch(void* const* d_in, const int* in_sizes, int n_in,
                              void* d_out, int out_size, void* d_ws, size_t ws_size,
                              hipStream_t stream) {
  const float* X     = (const float*)d_in[0];
  const float* Msk   = (const float*)d_in[1];
  const float* D     = (const float*)d_in[2];
  const float* Mean  = (const float*)d_in[3];
  const float* L     = (const float*)d_in[4];
  const float* w_gh  = (const float*)d_in[5];
  const float* b_gh  = (const float*)d_in[6];
  const float* w_gx  = (const float*)d_in[7];
  const float* b_gx  = (const float*)d_in[8];
  const float* w_ih  = (const float*)d_in[9];
  const float* w_hh  = (const float*)d_in[10];
  const float* b_ih  = (const float*)d_in[11];
  const float* b_hh  = (const float*)d_in[12];
  const float* w_cls = (const float*)d_in[13];
  const float* b_cls = (const float*)d_in[14];

  char* w = (char*)d_ws;
  bf16*  XRs   = (bf16*)(w);
  bf16*  Dbfs  = (bf16*)(w + 16777216);
  bf16*  GH    = (bf16*)(w + 25690112);
  bf16*  WcX3  = (bf16*)(w + 61341696);
  bf16*  WcH3  = (bf16*)(w + 65536000);
  bf16*  Wgs   = (bf16*)(w + 73924608);
  float* bias4 = (float*)(w + 74448896);
  float* hf0   = (float*)(w + 74465280);
  float* hf1   = (float*)(w + 78659584);
  bf16*  hb0   = (bf16*)(w + 82853888);
  bf16*  hb1   = (bf16*)(w + 84951040);
  bf16*  Gi    = (bf16*)(w + 87048192);

  size_t base = 87048192;
  int GCH = 16;
  while (GCH > 1 && base + (size_t)GCH * 6291456ull > ws_size) GCH >>= 1;

  float* hfp[2] = {hf0, hf1};
  bf16*  hbp[2] = {hb0, hb1};

  hipMemsetAsync(hf0, 0, 4194304, stream);
  hipMemsetAsync(hb0, 0, 2097152, stream);
  wprep_kernel<<<23568, 256, 0, stream>>>(w_ih, w_hh, b_ih, b_hh, w_gh, WcH3, WcX3, Wgs, bias4);

  int t = 0;
  for (int c = 0; c < 4; ++c) {
    int nsl = (c < 3) ? 17 : 16;
    prep_kernel<<<nsl * 1024, 256, 0, stream>>>(X, Msk, D, Mean, L, w_gx, b_gx, XRs, Dbfs, c, nsl);
    gammah_kernel<<<nsl * 64, 256, 0, stream>>>(Dbfs, Wgs, b_gh, GH);
    for (int sub = 0; sub < 16 / GCH; ++sub) {
      gix_kernel<<<GCH * 192, 256, 0, stream>>>(XRs + (size_t)sub * GCH * 524288, WcX3, Gi);
      for (int tl2 = 0; tl2 < GCH; ++tl2, ++t) {
        int tl = sub * GCH + tl2;
        int cur = t & 1, nxt = cur ^ 1;
        step_kernel<<<512, 512, 0, stream>>>(
            hbp[cur], hfp[cur], WcH3, bias4,
            Gi + (size_t)tl2 * 3145728, GH + (size_t)(tl + 1) * 1048576,
            (t == 63) ? 1 : 0, hfp[nxt], hbp[nxt]);
      }
    }
  }
  cls_kernel<<<256, 256, 0, stream>>>(hfp[0], w_cls, b_cls, (float*)d_out);
}